// Round 15
// baseline (350.168 us; speedup 1.0000x reference)
//
#include <hip/hip_runtime.h>
#include <hip/hip_bf16.h>

// ---------- constants ----------
#define NPOS   8192      // B*L
#define SEQL   2048
#define ZLD    2304      // z(1024) + xBC(1280) columns of in_proj
#define CONVD  1280
#define HOUT   40

using short4v = __attribute__((ext_vector_type(4))) short;
using short8  = __attribute__((ext_vector_type(8))) short;
using float2v = __attribute__((ext_vector_type(2))) float;
using float4v = __attribute__((ext_vector_type(4))) float;
using ushort4v= __attribute__((ext_vector_type(4))) unsigned short;
using double2v= __attribute__((ext_vector_type(2))) double;

__device__ __forceinline__ unsigned short f2b(float f) {
    unsigned x = __float_as_uint(f);
    unsigned r = x + 0x7fffu + ((x >> 16) & 1u);   // RNE
    return (unsigned short)(r >> 16);
}
__device__ __forceinline__ float b2f(unsigned short u) {
    union { unsigned u; float f; } c; c.u = ((unsigned)u) << 16; return c.f;
}
__device__ __forceinline__ float sigmoidf_(float x) { return 1.f / (1.f + __expf(-x)); }

__device__ __forceinline__ void gld16(const void* g, void* l) {
    __builtin_amdgcn_global_load_lds((const __attribute__((address_space(1))) void*)g,
                                     (__attribute__((address_space(3))) void*)l, 16, 0, 0);
}

// ---------- f32 -> bf16 conversion (4 elems/thread) ----------
__global__ __launch_bounds__(256) void cvt_bf16(
    const float* __restrict__ src, unsigned short* __restrict__ dst, int n4)
{
    int i = blockIdx.x * 256 + threadIdx.x;
    if (i >= n4) return;
    float4v v = *(const float4v*)(src + (size_t)i * 4);
    ushort4v o;
#pragma unroll
    for (int j = 0; j < 4; j++) o[j] = f2b(v[j]);
    *(ushort4v*)(dst + (size_t)i * 4) = o;
}

// ---------- classify the three size-16 tensors by content ----------
__global__ void canon16(const float* __restrict__ q0, const float* __restrict__ q1,
                        const float* __restrict__ q2, float* __restrict__ canon)
{
    const float* qs[3] = { q0, q1, q2 };
    int isD[3], isG[3];
#pragma unroll
    for (int j = 0; j < 3; j++) {
        int d = 1, g = 1;
        for (int i = 0; i < 16; i++) {
            unsigned b = __float_as_uint(qs[j][i]);
            d &= (b == 0x3F800000u);   // 1.0f
            g &= (b == 0x3DCCCCCDu);   // 0.1f
        }
        isD[j] = d; isG[j] = g;
    }
    int di = -1, gi = -1;
    for (int j = 0; j < 3; j++) { if (isD[j]) di = j; }
    for (int j = 0; j < 3; j++) { if (isG[j]) gi = j; }
    int ai;
    if (di < 0 || gi < 0 || di == gi) { gi = 0; ai = 1; di = 2; }
    else ai = 3 - di - gi;
    int t = threadIdx.x;
    if (t < 16) {
        canon[t]      = qs[gi][t];
        canon[16 + t] = qs[ai][t];
        canon[32 + t] = qs[di][t];
    }
}

// ---------- MFMA bf16 GEMM: C[M,N] = A[M,K] * W[N,K]^T ----------
// BK=64 (32 MFMA per barrier pair). LDS granule XOR-swizzle: physical granule q
// of row r holds logical granule q^(r&7) (pre-swizzled global source, linear
// global_load_lds dest, swizzled ds_read). 2-way bank access = free.
template<int OUT_BF16>
__global__ __launch_bounds__(256) void gemm_bt(
    const unsigned short* __restrict__ A, const unsigned short* __restrict__ W,
    float* __restrict__ Cf, unsigned short* __restrict__ Cb,
    int K, int lda, int ldw, int ldc)
{
    __shared__ unsigned short As[128 * 64];   // unpadded: global_load_lds layout
    __shared__ unsigned short Ws[128 * 64];
    const int m0 = blockIdx.x * 128, n0 = blockIdx.y * 128;
    const int tid = threadIdx.x;
    const int lane = tid & 63, wave = tid >> 6;
    const int wm = (wave & 1) * 64, wn = (wave >> 1) * 64;
    const int fr = lane & 15, fq = lane >> 4;
    const int fx = fr & 7;                    // read-side XOR key

    float4v acc[4][4];
#pragma unroll
    for (int i = 0; i < 4; i++)
#pragma unroll
        for (int j = 0; j < 4; j++) acc[i][j] = (float4v)0.f;

    for (int k0 = 0; k0 < K; k0 += 64) {
        if (k0) __syncthreads();
#pragma unroll
        for (int i = 0; i < 4; i++) {
            int g = i * 256 + tid;            // physical granule 0..1023 (16 B each)
            int row = g >> 3, q = g & 7;
            int ql = q ^ (row & 7);           // logical granule to fetch
            int lbase = (i * 256 + wave * 64) * 8;
            gld16(A + (size_t)(m0 + row) * lda + k0 + ql * 8, &As[lbase]);
            gld16(W + (size_t)(n0 + row) * ldw + k0 + ql * 8, &Ws[lbase]);
        }
        __syncthreads();
#pragma unroll
        for (int s = 0; s < 2; s++) {
            const int gq = (s * 4 + fq);      // logical granule of this fragment
            short8 af[4], wf[4];
#pragma unroll
            for (int i = 0; i < 4; i++)
                af[i] = *(const short8*)&As[(wm + i * 16 + fr) * 64 + (gq ^ fx) * 8];
#pragma unroll
            for (int j = 0; j < 4; j++)
                wf[j] = *(const short8*)&Ws[(wn + j * 16 + fr) * 64 + (gq ^ fx) * 8];
#pragma unroll
            for (int i = 0; i < 4; i++)
#pragma unroll
                for (int j = 0; j < 4; j++)
                    acc[i][j] = __builtin_amdgcn_mfma_f32_16x16x32_bf16(af[i], wf[j], acc[i][j], 0, 0, 0);
        }
    }
    const int cn = lane & 15, cr = (lane >> 4) * 4;   // C/D: col=lane&15, row=(lane>>4)*4+reg
#pragma unroll
    for (int i = 0; i < 4; i++) {
#pragma unroll
        for (int j = 0; j < 4; j++) {
            int gn = n0 + wn + j * 16 + cn;
#pragma unroll
            for (int r = 0; r < 4; r++) {
                int gm = m0 + wm + i * 16 + cr + r;
                if (OUT_BF16) Cb[(size_t)gm * ldc + gn] = f2b(acc[i][j][r]);
                else          Cf[(size_t)gm * ldc + gn] = acc[i][j][r];
            }
        }
    }
}

// ---------- weight repack (f32, contiguous [72][1024]) for the selection projection ----------
__global__ __launch_bounds__(256) void cvt_w32(
    const float* __restrict__ hw, const float* __restrict__ ipw,
    float* __restrict__ w32)
{
    int e = blockIdx.x;                 // 72
    int k = threadIdx.x * 4;
    const float* src = (e < 40) ? (hw + (size_t)e * 1056 + k)
                                : (ipw + (size_t)(2264 + e) * 1024 + k);
    *(float4v*)(w32 + (size_t)e * 1024 + k) = *(const float4v*)src;
}

// ---------- f64 selection projection v9: f32 weight loads, in-register widen ----------
// grid (128, 8), block 512: 64 rows x 128 k per block; wave = 9-e slice; lane = row.
// Weights via wave-uniform f32x4 scalar loads (half the K$ footprint of f64),
// widened in-register (exact). Per-acc FMA order identical to v5 -> bit-identical.
// Also emits u_bf (bf16 copy of u) as a staging byproduct.
__global__ __launch_bounds__(512) void proj_part(
    const float* __restrict__ u, const float* __restrict__ w32,
    double* __restrict__ pu72p, unsigned short* __restrict__ ub)
{
    __shared__ float us[64][132];
    int tid = threadIdx.x, lane = tid & 63;
    int rows0 = blockIdx.x * 64;
    int kb = blockIdx.y * 128;
    const int e0 = __builtin_amdgcn_readfirstlane((tid >> 6) * 9);
    double acc[9];
#pragma unroll
    for (int j = 0; j < 9; j++) acc[j] = 0.0;

#pragma unroll
    for (int i = 0; i < 4; i++) {
        int idx = i * 512 + tid;
        int row = idx >> 5, c4 = idx & 31;
        float4v v = *(const float4v*)(u + (size_t)(rows0 + row) * 1024 + kb + c4 * 4);
        *(float4v*)&us[row][c4 * 4] = v;
        ushort4v o;
#pragma unroll
        for (int j = 0; j < 4; j++) o[j] = f2b(v[j]);
        *(ushort4v*)(ub + (size_t)(rows0 + row) * 1024 + kb + c4 * 4) = o;
    }
    __syncthreads();
    for (int kk = 0; kk < 128; kk += 4) {
        float4v uv = *(const float4v*)&us[lane][kk];
        double u0 = (double)uv[0], u1 = (double)uv[1];
        double u2 = (double)uv[2], u3 = (double)uv[3];
        const float* wp = w32 + kb + kk;
#pragma unroll
        for (int j = 0; j < 9; j++) {
            float4v wv = *(const float4v*)(wp + (size_t)(e0 + j) * 1024);
            acc[j] += u0 * (double)wv[0] + u1 * (double)wv[1]
                    + u2 * (double)wv[2] + u3 * (double)wv[3];
        }
    }
    double* outp = pu72p + ((size_t)blockIdx.y * 8192 + rows0 + lane) * 72 + e0;
#pragma unroll
    for (int j = 0; j < 9; j++) outp[j] = acc[j];
}

// ---------- sum the 8 k-partials -> pu72 ----------
__global__ __launch_bounds__(256) void combine_pu(
    const double* __restrict__ pp, double* __restrict__ out)
{
    const double2v* p = (const double2v*)pp;
    size_t i = (size_t)blockIdx.x * 256 + threadIdx.x;   // 294912 double2
    double2v s = p[i];
#pragma unroll
    for (int c = 1; c < 8; c++) {
        double2v t = p[(size_t)c * 294912 + i];
        s[0] += t[0]; s[1] += t[1];
    }
    ((double2v*)out)[i] = s;
}

// ---------- prefix (f64) ----------
__global__ __launch_bounds__(256) void prefix_hbase(
    const double* __restrict__ pu72, double* __restrict__ hbase)
{
    int b = blockIdx.x / HOUT, e = blockIdx.x % HOUT;
    int tid = threadIdx.x, lane = tid & 63, wave = tid >> 6;
    __shared__ double wsum[4];
    double run = 0.0;
    for (int c = 0; c < 8; c++) {
        int l = c * 256 + tid;
        double v = pu72[(size_t)(b * SEQL + l) * 72 + e];
        double sv = v;
#pragma unroll
        for (int off = 1; off < 64; off <<= 1) {
            double tt = __shfl_up(sv, off, 64);
            if (lane >= off) sv += tt;
        }
        if (lane == 63) wsum[wave] = sv;
        __syncthreads();
        double pre = run;
        for (int w = 0; w < 4; w++) if (w < wave) pre += wsum[w];
        double total = wsum[0] + wsum[1] + wsum[2] + wsum[3];
        double incl = sv + pre;
        hbase[(size_t)(b * SEQL + l) * HOUT + e] = v - incl / (double)(l + 1);
        run += total;
        __syncthreads();
    }
}

// ---------- select (f64 scores): top-12 ranks -> dt/decay/log-decay per slot ----------
__global__ __launch_bounds__(256) void select_dt(
    const double* __restrict__ pu72, const double* __restrict__ hbase,
    const float* __restrict__ hw,
    const float* __restrict__ dt_bias, const float* __restrict__ canon,
    float* __restrict__ dtv, float* __restrict__ dec, float* __restrict__ ldv)
{
    const float* gamma = canon;        // [0..15]
    const float* A_log = canon + 16;   // [16..31]
    __shared__ float W2s[40][33];
    __shared__ double dts[4][33];
    __shared__ double hbs[4][44];
    int tid = threadIdx.x, lane = tid & 63, wave = tid >> 6;
    for (int idx = tid; idx < 1280; idx += 256) {
        int e = idx >> 5, f = idx & 31;
        W2s[e][f] = hw[(size_t)e * 1056 + 1024 + f];
    }
    int bl = blockIdx.x * 4 + wave;
    if (lane < 32) dts[wave][lane] = pu72[(size_t)bl * 72 + 40 + lane];
    __syncthreads();
    if (lane < 40) {
        double v = hbase[(size_t)bl * HOUT + lane];
#pragma unroll 8
        for (int f = 0; f < 32; f++) v += dts[wave][f] * (double)W2s[lane][f];
        hbs[wave][lane] = v;
    }
    __syncthreads();
    int slot = -1, id = -1;
    if (lane < 28) {
        double h = hbs[wave][lane];
        int rank = 0;
        for (int j = 0; j < 28; j++) {
            double hj = hbs[wave][j];
            rank += (hj > h) || (hj == h && j < lane);
        }
        if (rank < 12) { slot = rank; id = lane; }
    } else if (lane < 32) {
        slot = 12 + (lane - 28); id = lane;
    }
    if (slot >= 0) {
        double d = dts[wave][id] + (double)dt_bias[0];
        if (slot < 12) d += (double)gamma[slot] * hbs[wave][28 + slot];
        float df = (float)d;
        float sp = (df > 20.f) ? df : log1pf(__expf(df));
        float Ac = -__expf(A_log[slot]);
        dtv[(size_t)bl * 16 + slot] = sp;
        dec[(size_t)bl * 16 + slot] = __expf(sp * Ac);
        ldv[(size_t)bl * 16 + slot] = sp * Ac;     // log-decay for chunked scan
    }
}

// ---------- depthwise conv4 + bias + silu, 4 pos x 4 ch per thread ----------
__global__ __launch_bounds__(256) void conv_silu(
    const unsigned short* __restrict__ zx, const float* __restrict__ cw,
    const float* __restrict__ cb, float* __restrict__ out)
{
    int idx = blockIdx.x * 256 + threadIdx.x;   // 655360 = 2048 pos-groups x 320 ch-groups
    int cg = idx % 320, pg = idx / 320;
    int c4 = cg * 4;
    int bl0 = pg * 4;
    int l0 = bl0 & (SEQL - 1);

    ushort4v v[7];
#pragma unroll
    for (int i = 0; i < 7; i++) {
        int li = l0 + i - 3;
        if (li >= 0)
            v[i] = *(const ushort4v*)(zx + (size_t)(bl0 + i - 3) * ZLD + 1024 + c4);
        else
            v[i] = (ushort4v)0;
    }
    float4v wv[4];
#pragma unroll
    for (int j = 0; j < 4; j++) wv[j] = *(const float4v*)(cw + (size_t)(c4 + j) * 4);
    float4v cbv = *(const float4v*)(cb + c4);

#pragma unroll
    for (int r = 0; r < 4; r++) {
        float4v o;
#pragma unroll
        for (int j = 0; j < 4; j++) {
            float acc = cbv[j];
#pragma unroll
            for (int k = 0; k < 4; k++)
                acc += b2f(v[r + k][j]) * wv[j][k];
            o[j] = acc * sigmoidf_(acc);
        }
        *(float4v*)(out + (size_t)(bl0 + r) * CONVD + c4) = o;
    }
}

// ---------- per-chunk inclusive cumsum of log-decay; dt reorder; chunk product ----------
__global__ __launch_bounds__(256) void cumsum_ld(
    const float* __restrict__ ldv, const float* __restrict__ dtv,
    float* __restrict__ acum, float* __restrict__ dtc, float* __restrict__ Pch)
{
    int bx = blockIdx.x;               // (b*8+ck)*16+h
    int h = bx & 15, t2 = bx >> 4;     // t2 = b*8+ck
    int tid = threadIdx.x, lane = tid & 63, wave = tid >> 6;
    __shared__ float ws[4];
    size_t src = ((size_t)t2 * 256 + tid) * 16 + h;
    float v = ldv[src];
    float s = v;
#pragma unroll
    for (int off = 1; off < 64; off <<= 1) {
        float u = __shfl_up(s, off, 64);
        if (lane >= off) s += u;
    }
    if (lane == 63) ws[wave] = s;
    __syncthreads();
    float pre = 0.f;
    for (int w = 0; w < 4; w++) if (w < wave) pre += ws[w];
    float incl = s + pre;
    acum[(size_t)bx * 256 + tid] = incl;
    dtc[(size_t)bx * 256 + tid] = dtv[src];
    if (tid == 255) {
        int b = t2 >> 3, ck = t2 & 7;
        Pch[((b * 16 + h) * 8) + ck] = __expf(incl);   // full-chunk decay product
    }
}

// ---------- G[b,ck][t][s] = C_t . B_s  (bf16, lower block-triangle) ----------
__global__ __launch_bounds__(256) void gemm_G(
    const float* __restrict__ xc, unsigned short* __restrict__ Gg)
{
    __shared__ unsigned short Cs[128 * 40];
    __shared__ unsigned short Bs[128 * 40];
    const int z = blockIdx.x;          // b*8+ck
    const int tile = blockIdx.y;       // 0:(0,0) 1:(1,0) 2:(1,1)
    const int tb = (tile > 0) ? 1 : 0, sb = (tile > 1) ? 1 : 0;
    const int tid = threadIdx.x, lane = tid & 63, wave = tid >> 6;
    const int wm = (wave & 1) * 64, wn = (wave >> 1) * 64;
    const int fr = lane & 15, fq = lane >> 4;
    const size_t rowb = (size_t)z * 256;
    float4v acc[4][4];
#pragma unroll
    for (int i = 0; i < 4; i++)
#pragma unroll
        for (int j = 0; j < 4; j++) acc[i][j] = (float4v)0.f;
    for (int kc = 0; kc < 4; kc++) {
        __syncthreads();
#pragma unroll
        for (int g0 = 0; g0 < 4; g0++) {
            int g = g0 * 256 + tid;
            int r = g >> 3, c4 = (g & 7) * 4;
            float4v cv = *(const float4v*)(xc + (rowb + tb * 128 + r) * 1280 + 1152 + kc * 32 + c4);
            float4v bv = *(const float4v*)(xc + (rowb + sb * 128 + r) * 1280 + 1024 + kc * 32 + c4);
            ushort4v co, bo;
#pragma unroll
            for (int e = 0; e < 4; e++) { co[e] = f2b(cv[e]); bo[e] = f2b(bv[e]); }
            *(ushort4v*)&Cs[r * 40 + c4] = co;
            *(ushort4v*)&Bs[r * 40 + c4] = bo;
        }
        __syncthreads();
        short8 af[4], wf[4];
#pragma unroll
        for (int i = 0; i < 4; i++) af[i] = *(const short8*)&Cs[(wm + i * 16 + fr) * 40 + fq * 8];
#pragma unroll
        for (int j = 0; j < 4; j++) wf[j] = *(const short8*)&Bs[(wn + j * 16 + fr) * 40 + fq * 8];
#pragma unroll
        for (int i = 0; i < 4; i++)
#pragma unroll
            for (int j = 0; j < 4; j++)
                acc[i][j] = __builtin_amdgcn_mfma_f32_16x16x32_bf16(af[i], wf[j], acc[i][j], 0, 0, 0);
    }
#pragma unroll
    for (int i = 0; i < 4; i++)
#pragma unroll
        for (int j = 0; j < 4; j++) {
            int s = sb * 128 + wn + j * 16 + fr;
#pragma unroll
            for (int r = 0; r < 4; r++) {
                int t = tb * 128 + wm + i * 16 + fq * 4 + r;
                Gg[(rowb + t) * 256 + s] = f2b(acc[i][j][r]);
            }
        }
}

// ---------- chunk-final states via MFMA: S[p][n] = sum_t w_t x_t[p] B_t[n] ----------
// w_t = dtc_t * exp(a_end - acum_t). grid 448 = (b(4) x ck(7)) x h(16); 4 waves.
__global__ __launch_bounds__(256) void sstate_mm(
    const float* __restrict__ xc, const float* __restrict__ acum,
    const float* __restrict__ dtc, unsigned short* __restrict__ Sf)
{
    __shared__ unsigned short Xs[64 * 36];    // Xw^T tile [p][t], stride 36
    __shared__ unsigned short Bs[128 * 36];   // B^T tile [n][t], stride 36
    __shared__ float wS[256];
    const int bx = blockIdx.x;
    const int h = bx & 15, t2 = bx >> 4, ck = t2 % 7, b = t2 / 7;
    const int z = b * 8 + ck;
    const int tid = threadIdx.x, lane = tid & 63, wave = tid >> 6;
    const int fr = lane & 15, fq = lane >> 4;
    const size_t rowb = (size_t)z * 256;
    {
        int cbase = (z * 16 + h) * 256;
        float aend = acum[cbase + 255];
        wS[tid] = dtc[cbase + tid] * __expf(aend - acum[cbase + tid]);
    }
    float4v acc[4][2];
#pragma unroll
    for (int i = 0; i < 4; i++)
#pragma unroll
        for (int j = 0; j < 2; j++) acc[i][j] = (float4v)0.f;
    const int wn = wave * 32;

    for (int kc = 0; kc < 8; kc++) {
        const int t0 = kc * 32;
        __syncthreads();
        // stage B^T: Bs[n][t_local] (packed bf16 pairs)
#pragma unroll
        for (int i = 0; i < 8; i++) {
            int idx = i * 256 + tid;
            int n = idx & 127, s2 = idx >> 7;
            int srow = t0 + s2 * 2;
            float blo = xc[(rowb + srow) * 1280 + 1024 + n];
            float bhi = xc[(rowb + srow + 1) * 1280 + 1024 + n];
            unsigned pk = (unsigned)f2b(blo) | ((unsigned)f2b(bhi) << 16);
            *((unsigned*)Bs + n * 18 + s2) = pk;
        }
        // stage Xw^T: Xs[p][t_local] = bf16(x * w)
#pragma unroll
        for (int i = 0; i < 4; i++) {
            int idx = i * 256 + tid;
            int p = idx & 63, s2 = idx >> 6;
            int srow = t0 + s2 * 2;
            float xlo = xc[(rowb + srow) * 1280 + h * 64 + p] * wS[t0 + s2 * 2];
            float xhi = xc[(rowb + srow + 1) * 1280 + h * 64 + p] * wS[t0 + s2 * 2 + 1];
            unsigned pk = (unsigned)f2b(xlo) | ((unsigned)f2b(xhi) << 16);
            *((unsigned*)Xs + p * 18 + s2) = pk;
        }
        __syncthreads();
        short8 af[4], wf[2];
#pragma unroll
        for (int j = 0; j < 2; j++) wf[j] = *(const short8*)&Bs[(wn + j * 16 + fr) * 36 + fq * 8];
#pragma unroll
        for (int i = 0; i < 4; i++) af[i] = *(const short8*)&Xs[(i * 16 + fr) * 36 + fq * 8];
#pragma unroll
        for (int i = 0; i < 4; i++)
#pragma unroll
            for (int j = 0; j < 2; j++)
                acc[i][j] = __builtin_amdgcn_mfma_f32_16x16x32_bf16(af[i], wf[j], acc[i][j], 0, 0, 0);
    }
    const size_t so = (((size_t)(b * 16 + h) * 7 + ck) * 64) * 128;
#pragma unroll
    for (int i = 0; i < 4; i++)
#pragma unroll
        for (int j = 0; j < 2; j++) {
            int n = wn + j * 16 + fr;
#pragma unroll
            for (int r = 0; r < 4; r++) {
                int p = i * 16 + fq * 4 + r;
                Sf[so + (size_t)p * 128 + n] = f2b(acc[i][j][r]);
            }
        }
}

// ---------- combine per-chunk states into chunk-entry states Sin[ck] ----------
__global__ __launch_bounds__(256) void carry_state(
    const unsigned short* __restrict__ Sf, const float* __restrict__ Pch,
    unsigned short* __restrict__ Sin)
{
    int bh = blockIdx.x;               // b*16+h
    int tid = threadIdx.x;
    float S[32];
#pragma unroll
    for (int j = 0; j < 32; j++) S[j] = 0.f;
    const unsigned short* sl = Sf + (size_t)bh * 7 * 8192;
    unsigned short* so = Sin + ((size_t)bh * 8 + 1) * 8192;
    for (int cp = 0; cp < 7; cp++) {
        float P = Pch[bh * 8 + cp];
#pragma unroll
        for (int q = 0; q < 4; q++) {
            short8 a = *(const short8*)(sl + (size_t)cp * 8192 + q * 2048 + tid * 8);
            short8 o;
#pragma unroll
            for (int e = 0; e < 8; e++) {
                float v = S[q * 8 + e] * P + b2f((unsigned short)a[e]);
                S[q * 8 + e] = v;
                o[e] = (short)f2b(v);
            }
            *(short8*)(so + (size_t)cp * 8192 + q * 2048 + tid * 8) = o;
        }
    }
}

// ---------- chunked-SSD y: y = exp(a_t)*(C @ Sin^T) + (G.L) @ X + D*x ----------
// grid: 1024 = (b*8+ck)(32) x thalf(2) x h(16); block 256 (4 waves)
// wave w owns t-tiles (w+4i), i=0..1, within the block's 128-row t-half.
__global__ __launch_bounds__(256) void ymm(
    const float* __restrict__ xc, const unsigned short* __restrict__ Gg,
    const unsigned short* __restrict__ Sin, const float* __restrict__ acum,
    const float* __restrict__ dtc, const float* __restrict__ canon,
    float* __restrict__ y)
{
    __shared__ unsigned short Gs[128 * 40];   // G / Ct tile, stride 40 (16B-aligned, 2-way free)
    __shared__ unsigned short Xs[64 * 36];    // X^T tile, stride 36 (b64 reads, 4-way writes)
    __shared__ float aS[256];
    __shared__ float dS[256];
    const int bx = blockIdx.x;
    const int h = bx & 15, thalf = (bx >> 4) & 1, z = bx >> 5;   // z = b*8+ck
    const int ck = z & 7, b = z >> 3;
    const int tid = threadIdx.x, lane = tid & 63, wave = tid >> 6;
    const int fr = lane & 15, fq = lane >> 4;
    const int t0 = thalf * 128;
    {
        int cbase = (z * 16 + h) * 256;
        aS[tid] = acum[cbase + tid];
        dS[tid] = dtc[cbase + tid];
    }
    float4v acc[2][4];
#pragma unroll
    for (int i = 0; i < 2; i++)
#pragma unroll
        for (int j = 0; j < 4; j++) acc[i][j] = (float4v)0.f;
    const size_t rowb = (size_t)z * 256;

    // ---- inter-chunk: acc = C @ Sin^T, then scale rows by exp(a_t) ----
    if (ck) {
        const unsigned short* Sb = Sin + ((size_t)(b * 16 + h) * 8 + ck) * 8192;
        for (int nk = 0; nk < 4; nk++) {
            short8 wf[4];
#pragma unroll
            for (int j = 0; j < 4; j++)
                wf[j] = *(const short8*)(Sb + (size_t)(j * 16 + fr) * 128 + nk * 32 + fq * 8);
            __syncthreads();
#pragma unroll
            for (int g0 = 0; g0 < 4; g0++) {
                int g = g0 * 256 + tid;
                int r = g >> 3, c4 = (g & 7) * 4;
                float4v cv = *(const float4v*)(xc + (rowb + t0 + r) * 1280 + 1152 + nk * 32 + c4);
                ushort4v co;
#pragma unroll
                for (int e = 0; e < 4; e++) co[e] = f2b(cv[e]);
                *(ushort4v*)&Gs[r * 40 + c4] = co;
            }
            __syncthreads();
#pragma unroll
            for (int i = 0; i < 2; i++) {
                short8 af = *(const short8*)&Gs[((wave + 4 * i) * 16 + fr) * 40 + fq * 8];
#pragma unroll
                for (int j = 0; j < 4; j++)
                    acc[i][j] = __builtin_amdgcn_mfma_f32_16x16x32_bf16(af, wf[j], acc[i][j], 0, 0, 0);
            }
        }
#pragma unroll
        for (int i = 0; i < 2; i++) {
            int tb_ = t0 + (wave + 4 * i) * 16 + fq * 4;
            float e0 = __expf(aS[tb_]),     e1 = __expf(aS[tb_ + 1]);
            float e2 = __expf(aS[tb_ + 2]), e3 = __expf(aS[tb_ + 3]);
#pragma unroll
            for (int j = 0; j < 4; j++) {
                acc[i][j][0] *= e0; acc[i][j][1] *= e1;
                acc[i][j][2] *= e2; acc[i][j][3] *= e3;
            }
        }
    }

    // ---- intra-chunk: acc += (G . mask) @ X over s-blocks of 32 ----
    const int sbmax = thalf ? 8 : 4;
    for (int sbi = 0; sbi < sbmax; sbi++) {
        __syncthreads();
        // stage G rows [t0,t0+128) x s-block (bf16, global -> LDS stride 40)
#pragma unroll
        for (int g0 = 0; g0 < 2; g0++) {
            int g = g0 * 256 + tid;
            int r = g >> 2, q = (g & 3) * 8;
            *(short8*)&Gs[r * 40 + q] =
                *(const short8*)(Gg + (rowb + t0 + r) * 256 + sbi * 32 + q);
        }
        // stage X^T: Xs[p][s_local] = bf16(xc[s][h*64+p]) (b32 packed pairs)
#pragma unroll
        for (int k = 0; k < 4; k++) {
            int s2 = wave * 4 + k;
            int srow = sbi * 32 + s2 * 2;
            float xlo = xc[(rowb + srow) * 1280 + h * 64 + lane];
            float xhi = xc[(rowb + srow + 1) * 1280 + h * 64 + lane];
            unsigned pk = (unsigned)f2b(xlo) | ((unsigned)f2b(xhi) << 16);
            *((unsigned*)Xs + lane * 18 + s2) = pk;
        }
        __syncthreads();
        short8 wf[4];
#pragma unroll
        for (int j = 0; j < 4; j++) {
            const unsigned short* xr = &Xs[(j * 16 + fr) * 36 + fq * 8];
            short4v lo = *(const short4v*)xr;
            short4v hi = *(const short4v*)(xr + 4);
            short8 w;
            w[0] = lo[0]; w[1] = lo[1]; w[2] = lo[2]; w[3] = lo[3];
            w[4] = hi[0]; w[5] = hi[1]; w[6] = hi[2]; w[7] = hi[3];
            wf[j] = w;
        }
        const int s0 = sbi * 32 + fq * 8;
        float av[8], dv[8];
        {
            float4v aA = *(const float4v*)&aS[s0], aB = *(const float4v*)&aS[s0 + 4];
            float4v dA = *(const float4v*)&dS[s0], dB = *(const float4v*)&dS[s0 + 4];
#pragma unroll
            for (int e = 0; e < 4; e++) {
                av[e] = aA[e]; av[4 + e] = aB[e];
                dv[e] = dA[e]; dv[4 + e] = dB[e];
            }
        }
#pragma unroll
        for (int i = 0; i < 2; i++) {
            int gi = thalf * 8 + wave + 4 * i;       // global t-tile index
            if (gi >= 2 * sbi) {                     // tile touches s <= t region
                int tg = gi * 16 + fr;
                float at = aS[tg];
                short8 graw = *(const short8*)&Gs[((wave + 4 * i) * 16 + fr) * 40 + fq * 8];
                short8 m;
#pragma unroll
                for (int e = 0; e < 8; e++) {
                    float val = b2f((unsigned short)graw[e]) * dv[e] * __expf(at - av[e]);
                    m[e] = (s0 + e <= tg) ? (short)f2b(val) : (short)0;
                }
#pragma unroll
                for (int j = 0; j < 4; j++)
                    acc[i][j] = __builtin_amdgcn_mfma_f32_16x16x32_bf16(m, wf[j], acc[i][j], 0, 0, 0);
            }
        }
    }

    // ---- epilogue: y = acc + D*x ----
    const float Dh = canon[32 + h];
#pragma unroll
    for (int i = 0; i < 2; i++) {
        int trow = t0 + (wave + 4 * i) * 16 + fq * 4;
#pragma unroll
        for (int j = 0; j < 4; j++) {
            int pc = h * 64 + j * 16 + fr;
#pragma unroll
            for (int r = 0; r < 4; r++) {
                float xv = xc[(rowb + trow + r) * 1280 + pc];
                y[(rowb + trow + r) * 1024 + pc] = acc[i][j][r] + Dh * xv;
            }
        }
    }
}

// ---------- yz = y*silu(z); rmsnorm; -> bf16 yn ----------
__global__ __launch_bounds__(256) void rmsnorm_k(
    const float* __restrict__ y, const unsigned short* __restrict__ zx,
    const float* __restrict__ nw, unsigned short* __restrict__ out)
{
    int row = blockIdx.x, tid = threadIdx.x, lane = tid & 63, wave = tid >> 6;
    __shared__ float ws[4];
    float4v yv = *(const float4v*)(y + (size_t)row * 1024 + tid * 4);
    ushort4v zb = *(const ushort4v*)(zx + (size_t)row * ZLD + tid * 4);
    float yz[4]; float ss = 0.f;
#pragma unroll
    for (int i = 0; i < 4; i++) {
        float z = b2f(zb[i]);
        yz[i] = yv[i] * z * sigmoidf_(z);
        ss += yz[i] * yz[i];
    }
#pragma unroll
    for (int off = 1; off < 64; off <<= 1) ss += __shfl_xor(ss, off, 64);
    if (lane == 0) ws[wave] = ss;
    __syncthreads();
    float tot = ws[0] + ws[1] + ws[2] + ws[3];
    float scale = rsqrtf(tot / 1024.f + 1e-5f);
    ushort4v o;
#pragma unroll
    for (int i = 0; i < 4; i++) o[i] = f2b(yz[i] * scale * nw[tid * 4 + i]);
    *(ushort4v*)(out + (size_t)row * 1024 + tid * 4) = o;
}

// ---------- launch ----------
extern "C" void kernel_launch(void* const* d_in, const int* in_sizes, int n_in,
                              void* d_out, int out_size, void* d_ws, size_t ws_size,
                              hipStream_t stream)
{
    const float *u = nullptr, *in_proj = nullptr, *h_proj = nullptr, *conv_w = nullptr,
                *conv_b = nullptr, *dt_bias = nullptr, *norm_w = nullptr, *out_proj = nullptr;
    const float* q16[3] = { nullptr, nullptr, nullptr };
    int nq = 0;
    for (int i = 0; i < n_in; i++) {
        const float* p = (const float*)d_in[i];
        switch (in_sizes[i]) {
            case 8388608: u = p;        break;
            case 2392064: in_proj = p;  break;
            case 42240:   h_proj = p;   break;
            case 5120:    conv_w = p;   break;
            case 1280:    conv_b = p;   break;
            case 1:       dt_bias = p;  break;
            case 1024:    norm_w = p;   break;
            case 1048576: out_proj = p; break;
            case 16:      if (nq < 3) q16[nq++] = p; break;
            default: break;
        }
    }
    if (!u || !in_proj || !h_proj || !conv_w || !conv_b || !dt_bias || !norm_w || !out_proj || nq != 3) {
        u = (const float*)d_in[0]; in_proj = (const float*)d_in[1]; h_proj = (const float*)d_in[2];
        conv_w = (const float*)d_in[3]; conv_b = (const float*)d_in[4]; dt_bias = (const float*)d_in[5];
        q16[0] = (const float*)d_in[6]; q16[1] = (const float*)d_in[7]; q16[2] = (const float*)d_in[8];
        norm_w = (const float*)d_in[9]; out_proj = (const float*)d_in[10];
    }

    char* ws = (char*)d_ws;
    unsigned short* zx = (unsigned short*)(ws);              // 8192*2304 bf16 -> 37,748,736
    double* pu72  = (double*)(ws + 37748736);                // -> 42,467,328 (dead after select)
    double* hbase = (double*)(ws + 42467328);                // -> 45,088,768 (dead after select)
    unsigned short* Sf = (unsigned short*)(ws + 37748736);   // 7,340,032 B (aliases pu72+hbase)
    float*  dtv   = (float*) (ws + 45088768);                // -> 45,613,056
    float*  dec   = (float*) (ws + 45613056);                // -> 46,137,344
    float*  xc    = (float*) (ws + 46137344);                // 8192*1280 f32 -> 88,080,384
    double* pu72p = (double*)(ws + 46137344);                // aliases xc (dead until conv_silu): 37,748,736
    float*  w32   = (float*) (ws + 83886080);                // aliases xc tail: 294,912 -> 84,180,992
    float*  yb    = (float*) (ws + 88080384);                // 8192*1024 f32 -> 121,634,816
    unsigned short* u_bf = (unsigned short*)(ws + 88080384); // aliases yb: dead before ymm
    unsigned short* yn   = (unsigned short*)(ws + 121634816);// -> 138,412,032
    unsigned short* ip_bf= (unsigned short*)(ws + 138412032);// -> 143,130,624 (dead after gemm1)
    unsigned short* Gg   = (unsigned short*)(ws + 138412032);// aliases ip_bf: 4,194,304 B
    float*  ldv  = (float*) (ws + 142606336);                // tail of ip_bf region: 524,288 B
    unsigned short* op_bf= (unsigned short*)(ws + 143130624);// -> 145,227,776
    float*  canon = (float*) (ws + 145227776);               // 48 f32 -> 145,227,968
    float*  Pch   = (float*) (ws + 145227968);               // 512 f32 -> 145,230,016
    unsigned short* Sin  = (unsigned short*)(ws + 145230016);// 8,388,608 -> 153,618,624
    float*  acum = (float*) (ws + 153618624);                // 524,288 -> 154,142,912
    float*  dtc  = (float*) (ws + 154142912);                // 524,288 -> 154,667,200

    canon16<<<1, 64, 0, stream>>>(q16[0], q16[1], q16[2], canon);
    cvt_bf16<<<2304, 256, 0, stream>>>(in_proj, ip_bf, 589824);
    cvt_bf16<<<1024, 256, 0, stream>>>(out_proj, op_bf, 262144);

    cvt_w32<<<72, 256, 0, stream>>>(h_proj, in_proj, w32);
    proj_part<<<dim3(128, 8), 512, 0, stream>>>(u, w32, pu72p, u_bf);
    gemm_bt<1><<<dim3(64, 18), 256, 0, stream>>>(u_bf, ip_bf, nullptr, zx,
                                                 1024, 1024, 1024, ZLD);
    combine_pu<<<1152, 256, 0, stream>>>(pu72p, pu72);
    prefix_hbase<<<160, 256, 0, stream>>>(pu72, hbase);
    select_dt<<<2048, 256, 0, stream>>>(pu72, hbase, h_proj, dt_bias, canon, dtv, dec, ldv);
    conv_silu<<<2560, 256, 0, stream>>>(zx, conv_w, conv_b, xc);
    cumsum_ld<<<512, 256, 0, stream>>>(ldv, dtv, acum, dtc, Pch);
    gemm_G<<<dim3(32, 3), 256, 0, stream>>>(xc, Gg);
    sstate_mm<<<448, 256, 0, stream>>>(xc, acum, dtc, Sf);
    carry_state<<<64, 256, 0, stream>>>(Sf, Pch, Sin);
    ymm<<<1024, 256, 0, stream>>>(xc, Gg, Sin, acum, dtc, canon, yb);
    rmsnorm_k<<<NPOS, 256, 0, stream>>>(yb, zx, norm_w, yn);
    gemm_bt<0><<<dim3(64, 8), 256, 0, stream>>>(yn, op_bf, (float*)d_out, nullptr,
                                                1024, 1024, 1024, 1024);
}

// Round 16
// 336.581 us; speedup vs baseline: 1.0404x; 1.0404x over previous
//
#include <hip/hip_runtime.h>
#include <hip/hip_bf16.h>

// ---------- constants ----------
#define NPOS   8192      // B*L
#define SEQL   2048
#define ZLD    2304      // z(1024) + xBC(1280) columns of in_proj
#define CONVD  1280
#define HOUT   40

using short4v = __attribute__((ext_vector_type(4))) short;
using short8  = __attribute__((ext_vector_type(8))) short;
using float2v = __attribute__((ext_vector_type(2))) float;
using float4v = __attribute__((ext_vector_type(4))) float;
using ushort4v= __attribute__((ext_vector_type(4))) unsigned short;
using double2v= __attribute__((ext_vector_type(2))) double;

__device__ __forceinline__ unsigned short f2b(float f) {
    unsigned x = __float_as_uint(f);
    unsigned r = x + 0x7fffu + ((x >> 16) & 1u);   // RNE
    return (unsigned short)(r >> 16);
}
__device__ __forceinline__ float b2f(unsigned short u) {
    union { unsigned u; float f; } c; c.u = ((unsigned)u) << 16; return c.f;
}
__device__ __forceinline__ float sigmoidf_(float x) { return 1.f / (1.f + __expf(-x)); }

__device__ __forceinline__ void gld16(const void* g, void* l) {
    __builtin_amdgcn_global_load_lds((const __attribute__((address_space(1))) void*)g,
                                     (__attribute__((address_space(3))) void*)l, 16, 0, 0);
}

// ---------- f32 -> bf16 conversion (4 elems/thread) ----------
__global__ __launch_bounds__(256) void cvt_bf16(
    const float* __restrict__ src, unsigned short* __restrict__ dst, int n4)
{
    int i = blockIdx.x * 256 + threadIdx.x;
    if (i >= n4) return;
    float4v v = *(const float4v*)(src + (size_t)i * 4);
    ushort4v o;
#pragma unroll
    for (int j = 0; j < 4; j++) o[j] = f2b(v[j]);
    *(ushort4v*)(dst + (size_t)i * 4) = o;
}

// ---------- classify the three size-16 tensors by content ----------
__global__ void canon16(const float* __restrict__ q0, const float* __restrict__ q1,
                        const float* __restrict__ q2, float* __restrict__ canon)
{
    const float* qs[3] = { q0, q1, q2 };
    int isD[3], isG[3];
#pragma unroll
    for (int j = 0; j < 3; j++) {
        int d = 1, g = 1;
        for (int i = 0; i < 16; i++) {
            unsigned b = __float_as_uint(qs[j][i]);
            d &= (b == 0x3F800000u);   // 1.0f
            g &= (b == 0x3DCCCCCDu);   // 0.1f
        }
        isD[j] = d; isG[j] = g;
    }
    int di = -1, gi = -1;
    for (int j = 0; j < 3; j++) { if (isD[j]) di = j; }
    for (int j = 0; j < 3; j++) { if (isG[j]) gi = j; }
    int ai;
    if (di < 0 || gi < 0 || di == gi) { gi = 0; ai = 1; di = 2; }
    else ai = 3 - di - gi;
    int t = threadIdx.x;
    if (t < 16) {
        canon[t]      = qs[gi][t];
        canon[16 + t] = qs[ai][t];
        canon[32 + t] = qs[di][t];
    }
}

// ---------- MFMA bf16 GEMM: C[M,N] = A[M,K] * W[N,K]^T ----------
// BK=64 (32 MFMA per barrier pair). LDS granule XOR-swizzle: physical granule q
// of row r holds logical granule q^(r&7) (pre-swizzled global source, linear
// global_load_lds dest, swizzled ds_read). 2-way bank access = free.
template<int OUT_BF16>
__global__ __launch_bounds__(256) void gemm_bt(
    const unsigned short* __restrict__ A, const unsigned short* __restrict__ W,
    float* __restrict__ Cf, unsigned short* __restrict__ Cb,
    int K, int lda, int ldw, int ldc)
{
    __shared__ unsigned short As[128 * 64];   // unpadded: global_load_lds layout
    __shared__ unsigned short Ws[128 * 64];
    const int m0 = blockIdx.x * 128, n0 = blockIdx.y * 128;
    const int tid = threadIdx.x;
    const int lane = tid & 63, wave = tid >> 6;
    const int wm = (wave & 1) * 64, wn = (wave >> 1) * 64;
    const int fr = lane & 15, fq = lane >> 4;
    const int fx = fr & 7;                    // read-side XOR key

    float4v acc[4][4];
#pragma unroll
    for (int i = 0; i < 4; i++)
#pragma unroll
        for (int j = 0; j < 4; j++) acc[i][j] = (float4v)0.f;

    for (int k0 = 0; k0 < K; k0 += 64) {
        if (k0) __syncthreads();
#pragma unroll
        for (int i = 0; i < 4; i++) {
            int g = i * 256 + tid;            // physical granule 0..1023 (16 B each)
            int row = g >> 3, q = g & 7;
            int ql = q ^ (row & 7);           // logical granule to fetch
            int lbase = (i * 256 + wave * 64) * 8;
            gld16(A + (size_t)(m0 + row) * lda + k0 + ql * 8, &As[lbase]);
            gld16(W + (size_t)(n0 + row) * ldw + k0 + ql * 8, &Ws[lbase]);
        }
        __syncthreads();
#pragma unroll
        for (int s = 0; s < 2; s++) {
            const int gq = (s * 4 + fq);      // logical granule of this fragment
            short8 af[4], wf[4];
#pragma unroll
            for (int i = 0; i < 4; i++)
                af[i] = *(const short8*)&As[(wm + i * 16 + fr) * 64 + (gq ^ fx) * 8];
#pragma unroll
            for (int j = 0; j < 4; j++)
                wf[j] = *(const short8*)&Ws[(wn + j * 16 + fr) * 64 + (gq ^ fx) * 8];
#pragma unroll
            for (int i = 0; i < 4; i++)
#pragma unroll
                for (int j = 0; j < 4; j++)
                    acc[i][j] = __builtin_amdgcn_mfma_f32_16x16x32_bf16(af[i], wf[j], acc[i][j], 0, 0, 0);
        }
    }
    const int cn = lane & 15, cr = (lane >> 4) * 4;   // C/D: col=lane&15, row=(lane>>4)*4+reg
#pragma unroll
    for (int i = 0; i < 4; i++) {
#pragma unroll
        for (int j = 0; j < 4; j++) {
            int gn = n0 + wn + j * 16 + cn;
#pragma unroll
            for (int r = 0; r < 4; r++) {
                int gm = m0 + wm + i * 16 + cr + r;
                if (OUT_BF16) Cb[(size_t)gm * ldc + gn] = f2b(acc[i][j][r]);
                else          Cf[(size_t)gm * ldc + gn] = acc[i][j][r];
            }
        }
    }
}

// ---------- weight f32 -> f64 for the selection projection ----------
__global__ __launch_bounds__(256) void cvt_w64(
    const float* __restrict__ hw, const float* __restrict__ ipw,
    double* __restrict__ w64)
{
    int e = blockIdx.x;                 // 72
    int k = threadIdx.x * 4;
    const float* src = (e < 40) ? (hw + (size_t)e * 1056 + k)
                                : (ipw + (size_t)(2264 + e) * 1024 + k);
    float4v v = *(const float4v*)src;
    double* o = w64 + (size_t)e * 1024 + k;
    o[0] = (double)v[0]; o[1] = (double)v[1];
    o[2] = (double)v[2]; o[3] = (double)v[3];
}

// ---------- f64 selection projection v5: 8-way split-k, 8 waves x 9e ----------
// grid (128, 8), block 512: 64 rows x 128 k per block; wave = 9-e slice; lane = row.
// Weights via SGPR-uniform loads (readfirstlane on wave id); u via LDS.
// Also emits u_bf (bf16 copy of u) as a staging byproduct.
__global__ __launch_bounds__(512) void proj_part(
    const float* __restrict__ u, const double* __restrict__ w64,
    double* __restrict__ pu72p, unsigned short* __restrict__ ub)
{
    __shared__ float us[64][132];
    int tid = threadIdx.x, lane = tid & 63;
    int rows0 = blockIdx.x * 64;
    int kb = blockIdx.y * 128;
    const int e0 = __builtin_amdgcn_readfirstlane((tid >> 6) * 9);
    double acc[9];
#pragma unroll
    for (int j = 0; j < 9; j++) acc[j] = 0.0;

#pragma unroll
    for (int i = 0; i < 4; i++) {
        int idx = i * 512 + tid;
        int row = idx >> 5, c4 = idx & 31;
        float4v v = *(const float4v*)(u + (size_t)(rows0 + row) * 1024 + kb + c4 * 4);
        *(float4v*)&us[row][c4 * 4] = v;
        ushort4v o;
#pragma unroll
        for (int j = 0; j < 4; j++) o[j] = f2b(v[j]);
        *(ushort4v*)(ub + (size_t)(rows0 + row) * 1024 + kb + c4 * 4) = o;
    }
    __syncthreads();
    for (int kk = 0; kk < 128; kk += 4) {
        float4v uv = *(const float4v*)&us[lane][kk];
        double u0 = (double)uv[0], u1 = (double)uv[1];
        double u2 = (double)uv[2], u3 = (double)uv[3];
        const double* wp = w64 + kb + kk;
#pragma unroll
        for (int j = 0; j < 9; j++) {
            const double* w = wp + (size_t)(e0 + j) * 1024;
            acc[j] += u0 * w[0] + u1 * w[1] + u2 * w[2] + u3 * w[3];
        }
    }
    double* outp = pu72p + ((size_t)blockIdx.y * 8192 + rows0 + lane) * 72 + e0;
#pragma unroll
    for (int j = 0; j < 9; j++) outp[j] = acc[j];
}

// ---------- sum the 8 k-partials -> pu72 ----------
__global__ __launch_bounds__(256) void combine_pu(
    const double* __restrict__ pp, double* __restrict__ out)
{
    const double2v* p = (const double2v*)pp;
    size_t i = (size_t)blockIdx.x * 256 + threadIdx.x;   // 294912 double2
    double2v s = p[i];
#pragma unroll
    for (int c = 1; c < 8; c++) {
        double2v t = p[(size_t)c * 294912 + i];
        s[0] += t[0]; s[1] += t[1];
    }
    ((double2v*)out)[i] = s;
}

// ---------- prefix (f64) ----------
__global__ __launch_bounds__(256) void prefix_hbase(
    const double* __restrict__ pu72, double* __restrict__ hbase)
{
    int b = blockIdx.x / HOUT, e = blockIdx.x % HOUT;
    int tid = threadIdx.x, lane = tid & 63, wave = tid >> 6;
    __shared__ double wsum[4];
    double run = 0.0;
    for (int c = 0; c < 8; c++) {
        int l = c * 256 + tid;
        double v = pu72[(size_t)(b * SEQL + l) * 72 + e];
        double sv = v;
#pragma unroll
        for (int off = 1; off < 64; off <<= 1) {
            double tt = __shfl_up(sv, off, 64);
            if (lane >= off) sv += tt;
        }
        if (lane == 63) wsum[wave] = sv;
        __syncthreads();
        double pre = run;
        for (int w = 0; w < 4; w++) if (w < wave) pre += wsum[w];
        double total = wsum[0] + wsum[1] + wsum[2] + wsum[3];
        double incl = sv + pre;
        hbase[(size_t)(b * SEQL + l) * HOUT + e] = v - incl / (double)(l + 1);
        run += total;
        __syncthreads();
    }
}

// ---------- select (f64 scores): top-12 ranks -> dt/decay/log-decay per slot ----------
__global__ __launch_bounds__(256) void select_dt(
    const double* __restrict__ pu72, const double* __restrict__ hbase,
    const float* __restrict__ hw,
    const float* __restrict__ dt_bias, const float* __restrict__ canon,
    float* __restrict__ dtv, float* __restrict__ dec, float* __restrict__ ldv)
{
    const float* gamma = canon;        // [0..15]
    const float* A_log = canon + 16;   // [16..31]
    __shared__ float W2s[40][33];
    __shared__ double dts[4][33];
    __shared__ double hbs[4][44];
    int tid = threadIdx.x, lane = tid & 63, wave = tid >> 6;
    for (int idx = tid; idx < 1280; idx += 256) {
        int e = idx >> 5, f = idx & 31;
        W2s[e][f] = hw[(size_t)e * 1056 + 1024 + f];
    }
    int bl = blockIdx.x * 4 + wave;
    if (lane < 32) dts[wave][lane] = pu72[(size_t)bl * 72 + 40 + lane];
    __syncthreads();
    if (lane < 40) {
        double v = hbase[(size_t)bl * HOUT + lane];
#pragma unroll 8
        for (int f = 0; f < 32; f++) v += dts[wave][f] * (double)W2s[lane][f];
        hbs[wave][lane] = v;
    }
    __syncthreads();
    int slot = -1, id = -1;
    if (lane < 28) {
        double h = hbs[wave][lane];
        int rank = 0;
        for (int j = 0; j < 28; j++) {
            double hj = hbs[wave][j];
            rank += (hj > h) || (hj == h && j < lane);
        }
        if (rank < 12) { slot = rank; id = lane; }
    } else if (lane < 32) {
        slot = 12 + (lane - 28); id = lane;
    }
    if (slot >= 0) {
        double d = dts[wave][id] + (double)dt_bias[0];
        if (slot < 12) d += (double)gamma[slot] * hbs[wave][28 + slot];
        float df = (float)d;
        float sp = (df > 20.f) ? df : log1pf(__expf(df));
        float Ac = -__expf(A_log[slot]);
        dtv[(size_t)bl * 16 + slot] = sp;
        dec[(size_t)bl * 16 + slot] = __expf(sp * Ac);
        ldv[(size_t)bl * 16 + slot] = sp * Ac;     // log-decay for chunked scan
    }
}

// ---------- depthwise conv4 + bias + silu, 4 pos x 4 ch per thread ----------
__global__ __launch_bounds__(256) void conv_silu(
    const unsigned short* __restrict__ zx, const float* __restrict__ cw,
    const float* __restrict__ cb, float* __restrict__ out)
{
    int idx = blockIdx.x * 256 + threadIdx.x;   // 655360 = 2048 pos-groups x 320 ch-groups
    int cg = idx % 320, pg = idx / 320;
    int c4 = cg * 4;
    int bl0 = pg * 4;
    int l0 = bl0 & (SEQL - 1);

    ushort4v v[7];
#pragma unroll
    for (int i = 0; i < 7; i++) {
        int li = l0 + i - 3;
        if (li >= 0)
            v[i] = *(const ushort4v*)(zx + (size_t)(bl0 + i - 3) * ZLD + 1024 + c4);
        else
            v[i] = (ushort4v)0;
    }
    float4v wv[4];
#pragma unroll
    for (int j = 0; j < 4; j++) wv[j] = *(const float4v*)(cw + (size_t)(c4 + j) * 4);
    float4v cbv = *(const float4v*)(cb + c4);

#pragma unroll
    for (int r = 0; r < 4; r++) {
        float4v o;
#pragma unroll
        for (int j = 0; j < 4; j++) {
            float acc = cbv[j];
#pragma unroll
            for (int k = 0; k < 4; k++)
                acc += b2f(v[r + k][j]) * wv[j][k];
            o[j] = acc * sigmoidf_(acc);
        }
        *(float4v*)(out + (size_t)(bl0 + r) * CONVD + c4) = o;
    }
}

// ---------- per-chunk inclusive cumsum of log-decay; dt reorder; chunk product ----------
__global__ __launch_bounds__(256) void cumsum_ld(
    const float* __restrict__ ldv, const float* __restrict__ dtv,
    float* __restrict__ acum, float* __restrict__ dtc, float* __restrict__ Pch)
{
    int bx = blockIdx.x;               // (b*8+ck)*16+h
    int h = bx & 15, t2 = bx >> 4;     // t2 = b*8+ck
    int tid = threadIdx.x, lane = tid & 63, wave = tid >> 6;
    __shared__ float ws[4];
    size_t src = ((size_t)t2 * 256 + tid) * 16 + h;
    float v = ldv[src];
    float s = v;
#pragma unroll
    for (int off = 1; off < 64; off <<= 1) {
        float u = __shfl_up(s, off, 64);
        if (lane >= off) s += u;
    }
    if (lane == 63) ws[wave] = s;
    __syncthreads();
    float pre = 0.f;
    for (int w = 0; w < 4; w++) if (w < wave) pre += ws[w];
    float incl = s + pre;
    acum[(size_t)bx * 256 + tid] = incl;
    dtc[(size_t)bx * 256 + tid] = dtv[src];
    if (tid == 255) {
        int b = t2 >> 3, ck = t2 & 7;
        Pch[((b * 16 + h) * 8) + ck] = __expf(incl);   // full-chunk decay product
    }
}

// ---------- G[b,ck][t][s] = C_t . B_s  (bf16, lower block-triangle) ----------
__global__ __launch_bounds__(256) void gemm_G(
    const float* __restrict__ xc, unsigned short* __restrict__ Gg)
{
    __shared__ unsigned short Cs[128 * 40];
    __shared__ unsigned short Bs[128 * 40];
    const int z = blockIdx.x;          // b*8+ck
    const int tile = blockIdx.y;       // 0:(0,0) 1:(1,0) 2:(1,1)
    const int tb = (tile > 0) ? 1 : 0, sb = (tile > 1) ? 1 : 0;
    const int tid = threadIdx.x, lane = tid & 63, wave = tid >> 6;
    const int wm = (wave & 1) * 64, wn = (wave >> 1) * 64;
    const int fr = lane & 15, fq = lane >> 4;
    const size_t rowb = (size_t)z * 256;
    float4v acc[4][4];
#pragma unroll
    for (int i = 0; i < 4; i++)
#pragma unroll
        for (int j = 0; j < 4; j++) acc[i][j] = (float4v)0.f;
    for (int kc = 0; kc < 4; kc++) {
        __syncthreads();
#pragma unroll
        for (int g0 = 0; g0 < 4; g0++) {
            int g = g0 * 256 + tid;
            int r = g >> 3, c4 = (g & 7) * 4;
            float4v cv = *(const float4v*)(xc + (rowb + tb * 128 + r) * 1280 + 1152 + kc * 32 + c4);
            float4v bv = *(const float4v*)(xc + (rowb + sb * 128 + r) * 1280 + 1024 + kc * 32 + c4);
            ushort4v co, bo;
#pragma unroll
            for (int e = 0; e < 4; e++) { co[e] = f2b(cv[e]); bo[e] = f2b(bv[e]); }
            *(ushort4v*)&Cs[r * 40 + c4] = co;
            *(ushort4v*)&Bs[r * 40 + c4] = bo;
        }
        __syncthreads();
        short8 af[4], wf[4];
#pragma unroll
        for (int i = 0; i < 4; i++) af[i] = *(const short8*)&Cs[(wm + i * 16 + fr) * 40 + fq * 8];
#pragma unroll
        for (int j = 0; j < 4; j++) wf[j] = *(const short8*)&Bs[(wn + j * 16 + fr) * 40 + fq * 8];
#pragma unroll
        for (int i = 0; i < 4; i++)
#pragma unroll
            for (int j = 0; j < 4; j++)
                acc[i][j] = __builtin_amdgcn_mfma_f32_16x16x32_bf16(af[i], wf[j], acc[i][j], 0, 0, 0);
    }
#pragma unroll
    for (int i = 0; i < 4; i++)
#pragma unroll
        for (int j = 0; j < 4; j++) {
            int s = sb * 128 + wn + j * 16 + fr;
#pragma unroll
            for (int r = 0; r < 4; r++) {
                int t = tb * 128 + wm + i * 16 + fq * 4 + r;
                Gg[(rowb + t) * 256 + s] = f2b(acc[i][j][r]);
            }
        }
}

// ---------- chunk-final states via MFMA: S[p][n] = sum_t w_t x_t[p] B_t[n] ----------
// w_t = dtc_t * exp(a_end - acum_t). grid 448 = (b(4) x ck(7)) x h(16); 4 waves.
__global__ __launch_bounds__(256) void sstate_mm(
    const float* __restrict__ xc, const float* __restrict__ acum,
    const float* __restrict__ dtc, unsigned short* __restrict__ Sf)
{
    __shared__ unsigned short Xs[64 * 36];    // Xw^T tile [p][t], stride 36
    __shared__ unsigned short Bs[128 * 36];   // B^T tile [n][t], stride 36
    __shared__ float wS[256];
    const int bx = blockIdx.x;
    const int h = bx & 15, t2 = bx >> 4, ck = t2 % 7, b = t2 / 7;
    const int z = b * 8 + ck;
    const int tid = threadIdx.x, lane = tid & 63, wave = tid >> 6;
    const int fr = lane & 15, fq = lane >> 4;
    const size_t rowb = (size_t)z * 256;
    {
        int cbase = (z * 16 + h) * 256;
        float aend = acum[cbase + 255];
        wS[tid] = dtc[cbase + tid] * __expf(aend - acum[cbase + tid]);
    }
    float4v acc[4][2];
#pragma unroll
    for (int i = 0; i < 4; i++)
#pragma unroll
        for (int j = 0; j < 2; j++) acc[i][j] = (float4v)0.f;
    const int wn = wave * 32;

    for (int kc = 0; kc < 8; kc++) {
        const int t0 = kc * 32;
        __syncthreads();
        // stage B^T: Bs[n][t_local] (packed bf16 pairs)
#pragma unroll
        for (int i = 0; i < 8; i++) {
            int idx = i * 256 + tid;
            int n = idx & 127, s2 = idx >> 7;
            int srow = t0 + s2 * 2;
            float blo = xc[(rowb + srow) * 1280 + 1024 + n];
            float bhi = xc[(rowb + srow + 1) * 1280 + 1024 + n];
            unsigned pk = (unsigned)f2b(blo) | ((unsigned)f2b(bhi) << 16);
            *((unsigned*)Bs + n * 18 + s2) = pk;
        }
        // stage Xw^T: Xs[p][t_local] = bf16(x * w)
#pragma unroll
        for (int i = 0; i < 4; i++) {
            int idx = i * 256 + tid;
            int p = idx & 63, s2 = idx >> 6;
            int srow = t0 + s2 * 2;
            float xlo = xc[(rowb + srow) * 1280 + h * 64 + p] * wS[t0 + s2 * 2];
            float xhi = xc[(rowb + srow + 1) * 1280 + h * 64 + p] * wS[t0 + s2 * 2 + 1];
            unsigned pk = (unsigned)f2b(xlo) | ((unsigned)f2b(xhi) << 16);
            *((unsigned*)Xs + p * 18 + s2) = pk;
        }
        __syncthreads();
        short8 af[4], wf[2];
#pragma unroll
        for (int j = 0; j < 2; j++) wf[j] = *(const short8*)&Bs[(wn + j * 16 + fr) * 36 + fq * 8];
#pragma unroll
        for (int i = 0; i < 4; i++) af[i] = *(const short8*)&Xs[(i * 16 + fr) * 36 + fq * 8];
#pragma unroll
        for (int i = 0; i < 4; i++)
#pragma unroll
            for (int j = 0; j < 2; j++)
                acc[i][j] = __builtin_amdgcn_mfma_f32_16x16x32_bf16(af[i], wf[j], acc[i][j], 0, 0, 0);
    }
    const size_t so = (((size_t)(b * 16 + h) * 7 + ck) * 64) * 128;
#pragma unroll
    for (int i = 0; i < 4; i++)
#pragma unroll
        for (int j = 0; j < 2; j++) {
            int n = wn + j * 16 + fr;
#pragma unroll
            for (int r = 0; r < 4; r++) {
                int p = i * 16 + fq * 4 + r;
                Sf[so + (size_t)p * 128 + n] = f2b(acc[i][j][r]);
            }
        }
}

// ---------- combine per-chunk states into chunk-entry states Sin[ck] ----------
__global__ __launch_bounds__(256) void carry_state(
    const unsigned short* __restrict__ Sf, const float* __restrict__ Pch,
    unsigned short* __restrict__ Sin)
{
    int bh = blockIdx.x;               // b*16+h
    int tid = threadIdx.x;
    float S[32];
#pragma unroll
    for (int j = 0; j < 32; j++) S[j] = 0.f;
    const unsigned short* sl = Sf + (size_t)bh * 7 * 8192;
    unsigned short* so = Sin + ((size_t)bh * 8 + 1) * 8192;
    for (int cp = 0; cp < 7; cp++) {
        float P = Pch[bh * 8 + cp];
#pragma unroll
        for (int q = 0; q < 4; q++) {
            short8 a = *(const short8*)(sl + (size_t)cp * 8192 + q * 2048 + tid * 8);
            short8 o;
#pragma unroll
            for (int e = 0; e < 8; e++) {
                float v = S[q * 8 + e] * P + b2f((unsigned short)a[e]);
                S[q * 8 + e] = v;
                o[e] = (short)f2b(v);
            }
            *(short8*)(so + (size_t)cp * 8192 + q * 2048 + tid * 8) = o;
        }
    }
}

// ---------- chunked-SSD y: y = exp(a_t)*(C @ Sin^T) + (G.L) @ X + D*x ----------
// grid: 1024 = (b*8+ck)(32) x thalf(2) x h(16); block 256 (4 waves)
// wave w owns t-tiles (w+4i), i=0..1, within the block's 128-row t-half.
__global__ __launch_bounds__(256) void ymm(
    const float* __restrict__ xc, const unsigned short* __restrict__ Gg,
    const unsigned short* __restrict__ Sin, const float* __restrict__ acum,
    const float* __restrict__ dtc, const float* __restrict__ canon,
    float* __restrict__ y)
{
    __shared__ unsigned short Gs[128 * 40];   // G / Ct tile, stride 40 (16B-aligned, 2-way free)
    __shared__ unsigned short Xs[64 * 36];    // X^T tile, stride 36 (b64 reads, 4-way writes)
    __shared__ float aS[256];
    __shared__ float dS[256];
    const int bx = blockIdx.x;
    const int h = bx & 15, thalf = (bx >> 4) & 1, z = bx >> 5;   // z = b*8+ck
    const int ck = z & 7, b = z >> 3;
    const int tid = threadIdx.x, lane = tid & 63, wave = tid >> 6;
    const int fr = lane & 15, fq = lane >> 4;
    const int t0 = thalf * 128;
    {
        int cbase = (z * 16 + h) * 256;
        aS[tid] = acum[cbase + tid];
        dS[tid] = dtc[cbase + tid];
    }
    float4v acc[2][4];
#pragma unroll
    for (int i = 0; i < 2; i++)
#pragma unroll
        for (int j = 0; j < 4; j++) acc[i][j] = (float4v)0.f;
    const size_t rowb = (size_t)z * 256;

    // ---- inter-chunk: acc = C @ Sin^T, then scale rows by exp(a_t) ----
    if (ck) {
        const unsigned short* Sb = Sin + ((size_t)(b * 16 + h) * 8 + ck) * 8192;
        for (int nk = 0; nk < 4; nk++) {
            short8 wf[4];
#pragma unroll
            for (int j = 0; j < 4; j++)
                wf[j] = *(const short8*)(Sb + (size_t)(j * 16 + fr) * 128 + nk * 32 + fq * 8);
            __syncthreads();
#pragma unroll
            for (int g0 = 0; g0 < 4; g0++) {
                int g = g0 * 256 + tid;
                int r = g >> 3, c4 = (g & 7) * 4;
                float4v cv = *(const float4v*)(xc + (rowb + t0 + r) * 1280 + 1152 + nk * 32 + c4);
                ushort4v co;
#pragma unroll
                for (int e = 0; e < 4; e++) co[e] = f2b(cv[e]);
                *(ushort4v*)&Gs[r * 40 + c4] = co;
            }
            __syncthreads();
#pragma unroll
            for (int i = 0; i < 2; i++) {
                short8 af = *(const short8*)&Gs[((wave + 4 * i) * 16 + fr) * 40 + fq * 8];
#pragma unroll
                for (int j = 0; j < 4; j++)
                    acc[i][j] = __builtin_amdgcn_mfma_f32_16x16x32_bf16(af, wf[j], acc[i][j], 0, 0, 0);
            }
        }
#pragma unroll
        for (int i = 0; i < 2; i++) {
            int tb_ = t0 + (wave + 4 * i) * 16 + fq * 4;
            float e0 = __expf(aS[tb_]),     e1 = __expf(aS[tb_ + 1]);
            float e2 = __expf(aS[tb_ + 2]), e3 = __expf(aS[tb_ + 3]);
#pragma unroll
            for (int j = 0; j < 4; j++) {
                acc[i][j][0] *= e0; acc[i][j][1] *= e1;
                acc[i][j][2] *= e2; acc[i][j][3] *= e3;
            }
        }
    }

    // ---- intra-chunk: acc += (G . mask) @ X over s-blocks of 32 ----
    const int sbmax = thalf ? 8 : 4;
    for (int sbi = 0; sbi < sbmax; sbi++) {
        __syncthreads();
        // stage G rows [t0,t0+128) x s-block (bf16, global -> LDS stride 40)
#pragma unroll
        for (int g0 = 0; g0 < 2; g0++) {
            int g = g0 * 256 + tid;
            int r = g >> 2, q = (g & 3) * 8;
            *(short8*)&Gs[r * 40 + q] =
                *(const short8*)(Gg + (rowb + t0 + r) * 256 + sbi * 32 + q);
        }
        // stage X^T: Xs[p][s_local] = bf16(xc[s][h*64+p]) (b32 packed pairs)
#pragma unroll
        for (int k = 0; k < 4; k++) {
            int s2 = wave * 4 + k;
            int srow = sbi * 32 + s2 * 2;
            float xlo = xc[(rowb + srow) * 1280 + h * 64 + lane];
            float xhi = xc[(rowb + srow + 1) * 1280 + h * 64 + lane];
            unsigned pk = (unsigned)f2b(xlo) | ((unsigned)f2b(xhi) << 16);
            *((unsigned*)Xs + lane * 18 + s2) = pk;
        }
        __syncthreads();
        short8 wf[4];
#pragma unroll
        for (int j = 0; j < 4; j++) {
            const unsigned short* xr = &Xs[(j * 16 + fr) * 36 + fq * 8];
            short4v lo = *(const short4v*)xr;
            short4v hi = *(const short4v*)(xr + 4);
            short8 w;
            w[0] = lo[0]; w[1] = lo[1]; w[2] = lo[2]; w[3] = lo[3];
            w[4] = hi[0]; w[5] = hi[1]; w[6] = hi[2]; w[7] = hi[3];
            wf[j] = w;
        }
        const int s0 = sbi * 32 + fq * 8;
        float av[8], dv[8];
        {
            float4v aA = *(const float4v*)&aS[s0], aB = *(const float4v*)&aS[s0 + 4];
            float4v dA = *(const float4v*)&dS[s0], dB = *(const float4v*)&dS[s0 + 4];
#pragma unroll
            for (int e = 0; e < 4; e++) {
                av[e] = aA[e]; av[4 + e] = aB[e];
                dv[e] = dA[e]; dv[4 + e] = dB[e];
            }
        }
#pragma unroll
        for (int i = 0; i < 2; i++) {
            int gi = thalf * 8 + wave + 4 * i;       // global t-tile index
            if (gi >= 2 * sbi) {                     // tile touches s <= t region
                int tg = gi * 16 + fr;
                float at = aS[tg];
                short8 graw = *(const short8*)&Gs[((wave + 4 * i) * 16 + fr) * 40 + fq * 8];
                short8 m;
#pragma unroll
                for (int e = 0; e < 8; e++) {
                    float val = b2f((unsigned short)graw[e]) * dv[e] * __expf(at - av[e]);
                    m[e] = (s0 + e <= tg) ? (short)f2b(val) : (short)0;
                }
#pragma unroll
                for (int j = 0; j < 4; j++)
                    acc[i][j] = __builtin_amdgcn_mfma_f32_16x16x32_bf16(m, wf[j], acc[i][j], 0, 0, 0);
            }
        }
    }

    // ---- epilogue: y = acc + D*x ----
    const float Dh = canon[32 + h];
#pragma unroll
    for (int i = 0; i < 2; i++) {
        int trow = t0 + (wave + 4 * i) * 16 + fq * 4;
#pragma unroll
        for (int j = 0; j < 4; j++) {
            int pc = h * 64 + j * 16 + fr;
#pragma unroll
            for (int r = 0; r < 4; r++) {
                float xv = xc[(rowb + trow + r) * 1280 + pc];
                y[(rowb + trow + r) * 1024 + pc] = acc[i][j][r] + Dh * xv;
            }
        }
    }
}

// ---------- yz = y*silu(z); rmsnorm; -> bf16 yn ----------
__global__ __launch_bounds__(256) void rmsnorm_k(
    const float* __restrict__ y, const unsigned short* __restrict__ zx,
    const float* __restrict__ nw, unsigned short* __restrict__ out)
{
    int row = blockIdx.x, tid = threadIdx.x, lane = tid & 63, wave = tid >> 6;
    __shared__ float ws[4];
    float4v yv = *(const float4v*)(y + (size_t)row * 1024 + tid * 4);
    ushort4v zb = *(const ushort4v*)(zx + (size_t)row * ZLD + tid * 4);
    float yz[4]; float ss = 0.f;
#pragma unroll
    for (int i = 0; i < 4; i++) {
        float z = b2f(zb[i]);
        yz[i] = yv[i] * z * sigmoidf_(z);
        ss += yz[i] * yz[i];
    }
#pragma unroll
    for (int off = 1; off < 64; off <<= 1) ss += __shfl_xor(ss, off, 64);
    if (lane == 0) ws[wave] = ss;
    __syncthreads();
    float tot = ws[0] + ws[1] + ws[2] + ws[3];
    float scale = rsqrtf(tot / 1024.f + 1e-5f);
    ushort4v o;
#pragma unroll
    for (int i = 0; i < 4; i++) o[i] = f2b(yz[i] * scale * nw[tid * 4 + i]);
    *(ushort4v*)(out + (size_t)row * 1024 + tid * 4) = o;
}

// ---------- launch ----------
extern "C" void kernel_launch(void* const* d_in, const int* in_sizes, int n_in,
                              void* d_out, int out_size, void* d_ws, size_t ws_size,
                              hipStream_t stream)
{
    const float *u = nullptr, *in_proj = nullptr, *h_proj = nullptr, *conv_w = nullptr,
                *conv_b = nullptr, *dt_bias = nullptr, *norm_w = nullptr, *out_proj = nullptr;
    const float* q16[3] = { nullptr, nullptr, nullptr };
    int nq = 0;
    for (int i = 0; i < n_in; i++) {
        const float* p = (const float*)d_in[i];
        switch (in_sizes[i]) {
            case 8388608: u = p;        break;
            case 2392064: in_proj = p;  break;
            case 42240:   h_proj = p;   break;
            case 5120:    conv_w = p;   break;
            case 1280:    conv_b = p;   break;
            case 1:       dt_bias = p;  break;
            case 1024:    norm_w = p;   break;
            case 1048576: out_proj = p; break;
            case 16:      if (nq < 3) q16[nq++] = p; break;
            default: break;
        }
    }
    if (!u || !in_proj || !h_proj || !conv_w || !conv_b || !dt_bias || !norm_w || !out_proj || nq != 3) {
        u = (const float*)d_in[0]; in_proj = (const float*)d_in[1]; h_proj = (const float*)d_in[2];
        conv_w = (const float*)d_in[3]; conv_b = (const float*)d_in[4]; dt_bias = (const float*)d_in[5];
        q16[0] = (const float*)d_in[6]; q16[1] = (const float*)d_in[7]; q16[2] = (const float*)d_in[8];
        norm_w = (const float*)d_in[9]; out_proj = (const float*)d_in[10];
    }

    char* ws = (char*)d_ws;
    unsigned short* zx = (unsigned short*)(ws);              // 8192*2304 bf16 -> 37,748,736
    double* pu72  = (double*)(ws + 37748736);                // -> 42,467,328 (dead after select)
    double* hbase = (double*)(ws + 42467328);                // -> 45,088,768 (dead after select)
    unsigned short* Sf = (unsigned short*)(ws + 37748736);   // 7,340,032 B (aliases pu72+hbase)
    float*  dtv   = (float*) (ws + 45088768);                // -> 45,613,056
    float*  dec   = (float*) (ws + 45613056);                // -> 46,137,344
    float*  xc    = (float*) (ws + 46137344);                // 8192*1280 f32 -> 88,080,384
    double* pu72p = (double*)(ws + 46137344);                // aliases xc (dead until conv_silu): 37,748,736
    double* w64   = (double*)(ws + 83886080);                // aliases xc tail: 589,824 -> 84,475,904
    float*  yb    = (float*) (ws + 88080384);                // 8192*1024 f32 -> 121,634,816
    unsigned short* u_bf = (unsigned short*)(ws + 88080384); // aliases yb: dead before ymm
    unsigned short* yn   = (unsigned short*)(ws + 121634816);// -> 138,412,032
    unsigned short* ip_bf= (unsigned short*)(ws + 138412032);// -> 143,130,624 (dead after gemm1)
    unsigned short* Gg   = (unsigned short*)(ws + 138412032);// aliases ip_bf: 4,194,304 B
    float*  ldv  = (float*) (ws + 142606336);                // tail of ip_bf region: 524,288 B
    unsigned short* op_bf= (unsigned short*)(ws + 143130624);// -> 145,227,776
    float*  canon = (float*) (ws + 145227776);               // 48 f32 -> 145,227,968
    float*  Pch   = (float*) (ws + 145227968);               // 512 f32 -> 145,230,016
    unsigned short* Sin  = (unsigned short*)(ws + 145230016);// 8,388,608 -> 153,618,624
    float*  acum = (float*) (ws + 153618624);                // 524,288 -> 154,142,912
    float*  dtc  = (float*) (ws + 154142912);                // 524,288 -> 154,667,200

    canon16<<<1, 64, 0, stream>>>(q16[0], q16[1], q16[2], canon);
    cvt_bf16<<<2304, 256, 0, stream>>>(in_proj, ip_bf, 589824);
    cvt_bf16<<<1024, 256, 0, stream>>>(out_proj, op_bf, 262144);

    cvt_w64<<<72, 256, 0, stream>>>(h_proj, in_proj, w64);
    proj_part<<<dim3(128, 8), 512, 0, stream>>>(u, w64, pu72p, u_bf);
    gemm_bt<1><<<dim3(64, 18), 256, 0, stream>>>(u_bf, ip_bf, nullptr, zx,
                                                 1024, 1024, 1024, ZLD);
    combine_pu<<<1152, 256, 0, stream>>>(pu72p, pu72);
    prefix_hbase<<<160, 256, 0, stream>>>(pu72, hbase);
    select_dt<<<2048, 256, 0, stream>>>(pu72, hbase, h_proj, dt_bias, canon, dtv, dec, ldv);
    conv_silu<<<2560, 256, 0, stream>>>(zx, conv_w, conv_b, xc);
    cumsum_ld<<<512, 256, 0, stream>>>(ldv, dtv, acum, dtc, Pch);
    gemm_G<<<dim3(32, 3), 256, 0, stream>>>(xc, Gg);
    sstate_mm<<<448, 256, 0, stream>>>(xc, acum, dtc, Sf);
    carry_state<<<64, 256, 0, stream>>>(Sf, Pch, Sin);
    ymm<<<1024, 256, 0, stream>>>(xc, Gg, Sin, acum, dtc, canon, yb);
    rmsnorm_k<<<NPOS, 256, 0, stream>>>(yb, zx, norm_w, yn);
    gemm_bt<0><<<dim3(64, 8), 256, 0, stream>>>(yn, op_bf, (float*)d_out, nullptr,
                                                1024, 1024, 1024, 1024);
}